// Round 13
// baseline (534.604 us; speedup 1.0000x reference)
//
#include <hip/hip_runtime.h>

#define NU 100000
#define NI 200000
#define NE 1000000
#define NB 4096
#define CAP 16384
#define NBS 98   // src buckets: ceil(100000/1024), shift 10
#define NBD 98   // dst buckets: ceil(200000/2048), shift 11
#define NTI (NI / 16)
#define NTU (NU / 16)

typedef __attribute__((ext_vector_type(8))) short bf16x8;
typedef __attribute__((ext_vector_type(4))) float f32x4;
typedef __attribute__((ext_vector_type(8))) unsigned short u16x8;

static __device__ __forceinline__ short f2bf(float f) {
  unsigned u = __builtin_bit_cast(unsigned, f);
  unsigned r = (u + 0x7fffu + ((u >> 16) & 1u)) >> 16;
  return (short)r;
}
static __device__ __forceinline__ float bf2f(unsigned short u) {
  return __builtin_bit_cast(float, ((unsigned)u) << 16);
}

// ====== binA: per-block LDS histogram + run reservation + direct scatter to bucket arena ======
__global__ __launch_bounds__(256) void binA_kernel(const int* __restrict__ src,
                                                   const int* __restrict__ dst,
                                                   int* __restrict__ gcur_s,
                                                   int* __restrict__ gcur_d,
                                                   int2* __restrict__ temp_s,
                                                   int2* __restrict__ temp_d) {
  __shared__ int lh[128], lbase[128], lpos[128];
  const int dir = blockIdx.x >> 9;          // 0 = src, 1 = dst
  const int cb = blockIdx.x & 511;
  const int lo = (int)(((long long)NE * cb) >> 9);
  const int hi = (int)(((long long)NE * (cb + 1)) >> 9);
  const int* key = dir ? dst : src;
  const int* oth = dir ? src : dst;
  int* gcur = dir ? gcur_d : gcur_s;
  int2* temp = dir ? temp_d : temp_s;
  const int shift = dir ? 11 : 10;
  const int tid = threadIdx.x;
  if (tid < 128) lh[tid] = 0;
  __syncthreads();
  for (int e = lo + tid; e < hi; e += 256) atomicAdd(&lh[key[e] >> shift], 1);
  __syncthreads();
  if (tid < 128) {
    const int c = lh[tid];
    lbase[tid] = c ? atomicAdd(&gcur[tid], c) : 0;
    lpos[tid] = 0;
  }
  __syncthreads();
  for (int e = lo + tid; e < hi; e += 256) {
    const int k = key[e];
    const int b = k >> shift;
    const int p = lbase[b] + atomicAdd(&lpos[b], 1);
    temp[(size_t)b * CAP + p] = make_int2(k, oth[e]);
  }
}

// ====== tiny serial scan of bucket totals ======
__global__ void bktscan_kernel(const int* __restrict__ gcur_s, const int* __restrict__ gcur_d,
                               int* __restrict__ bktofs_s, int* __restrict__ bktofs_d,
                               int* __restrict__ ofs_u, int* __restrict__ ofs_i) {
  const int t = threadIdx.x;
  if (t == 0) {
    int a = 0;
    for (int i = 0; i < NBS; ++i) { bktofs_s[i] = a; a += gcur_s[i]; }
    bktofs_s[NBS] = a;
    ofs_u[NU] = NE;
  }
  if (t == 1) {
    int a = 0;
    for (int i = 0; i < NBD; ++i) { bktofs_d[i] = a; a += gcur_d[i]; }
    bktofs_d[NBD] = a;
    ofs_i[NI] = NE;
  }
}

// ====== placeB: per-bucket LDS counting sort -> ofs, rs, CSR payload (nbr only, 4B) ======
__global__ __launch_bounds__(256) void placeB_kernel(const int2* __restrict__ temp_s,
                                                     const int2* __restrict__ temp_d,
                                                     const int* __restrict__ gcur_s,
                                                     const int* __restrict__ gcur_d,
                                                     const int* __restrict__ bktofs_s,
                                                     const int* __restrict__ bktofs_d,
                                                     int* __restrict__ ofs_u, int* __restrict__ ofs_i,
                                                     float* __restrict__ rs_u, float* __restrict__ rs_i,
                                                     int* __restrict__ by_src, int* __restrict__ by_dst) {
  __shared__ int cnt[2048];
  __shared__ int exc[2048];
  __shared__ int wsum[256];
  const bool isdst = blockIdx.x >= NBS;
  const int b = isdst ? (int)blockIdx.x - NBS : (int)blockIdx.x;
  const int shift = isdst ? 11 : 10;
  const int nodelo = b << shift;
  const int n = isdst ? NI : NU;
  const int2* temp = (isdst ? temp_d : temp_s) + (size_t)b * CAP;
  const int ecnt = (isdst ? gcur_d : gcur_s)[b];
  const int bbase = (isdst ? bktofs_d : bktofs_s)[b];
  int* ofs = isdst ? ofs_i : ofs_u;
  float* rs = isdst ? rs_i : rs_u;
  int* by = isdst ? by_dst : by_src;
  const int tid = threadIdx.x;
  const int NN = 1 << shift;  // 1024 or 2048

  for (int j = tid; j < NN; j += 256) cnt[j] = 0;
  __syncthreads();
  for (int k = tid; k < ecnt; k += 256) atomicAdd(&cnt[temp[k].x - nodelo], 1);
  __syncthreads();
  const int per = NN >> 8;  // 4 or 8
  int s = 0;
  for (int j = 0; j < per; ++j) s += cnt[tid * per + j];
  wsum[tid] = s;
  __syncthreads();
  for (int off = 1; off < 256; off <<= 1) {
    int t2 = (tid >= off) ? wsum[tid - off] : 0;
    __syncthreads();
    wsum[tid] += t2;
    __syncthreads();
  }
  int run = wsum[tid] - s;
  for (int j = 0; j < per; ++j) {
    const int idx = tid * per + j;
    exc[idx] = run;
    run += cnt[idx];
  }
  __syncthreads();
  for (int j = tid; j < NN; j += 256) {
    const int node = nodelo + j;
    if (node < n) {
      ofs[node] = bbase + exc[j];
      const int d = cnt[j];
      rs[node] = d > 0 ? rsqrtf((float)d) : 0.f;
    }
  }
  __syncthreads();
  for (int j = tid; j < NN; j += 256) cnt[j] = exc[j];  // cnt becomes cursor
  __syncthreads();
  for (int k = tid; k < ecnt; k += 256) {
    const int2 t2 = temp[k];
    const int p = bbase + atomicAdd(&cnt[t2.x - nodelo], 1);
    by[p] = t2.y;
  }
}

// ====== cw: weighted payload byw = {nbr, rs_nb} and layer-invariant c = rs_r * sum rs_nb ======
__global__ __launch_bounds__(256) void cw_kernel(const int* __restrict__ ofs_i,
                                                 const int* __restrict__ ofs_u,
                                                 const int* __restrict__ by_dst,
                                                 const int* __restrict__ by_src,
                                                 const float* __restrict__ rs_u,
                                                 const float* __restrict__ rs_i,
                                                 int2* __restrict__ byw_dst,
                                                 int2* __restrict__ byw_src,
                                                 float* __restrict__ c_i,
                                                 float* __restrict__ c_u) {
  int r = blockIdx.x * 256 + threadIdx.x;
  if (r < NI) {
    const int lo = ofs_i[r], hi = ofs_i[r + 1];
    float s = 0.f;
    for (int k = lo; k < hi; ++k) {
      const int nb = by_dst[k];
      const float w = rs_u[nb];
      byw_dst[k] = make_int2(nb, __builtin_bit_cast(int, w));
      s += w;
    }
    c_i[r] = rs_i[r] * s;
  } else if (r < NI + NU) {
    r -= NI;
    const int lo = ofs_u[r], hi = ofs_u[r + 1];
    float s = 0.f;
    for (int k = lo; k < hi; ++k) {
      const int nb = by_src[k];
      const float w = rs_i[nb];
      byw_src[k] = make_int2(nb, __builtin_bit_cast(int, w));
      s += w;
    }
    c_u[r] = rs_u[r] * s;
  }
}

// ====== conv: f32 -> bf16 h ======
__global__ __launch_bounds__(256) void conv_kernel(const float* __restrict__ uf,
                                                   const float* __restrict__ itf,
                                                   unsigned short* __restrict__ hu,
                                                   unsigned short* __restrict__ hi) {
  int i = blockIdx.x * 256 + threadIdx.x;
  const int n4u = NU * 16;
  const float* in;
  unsigned short* outp;
  int j;
  if (i < n4u) {
    in = uf; outp = hu; j = i;
  } else if (i < n4u + NI * 16) {
    in = itf; outp = hi; j = i - n4u;
  } else return;
  float4 v = *(const float4*)&in[(size_t)j * 4];
  ushort4 o;
  o.x = (unsigned short)f2bf(v.x);
  o.y = (unsigned short)f2bf(v.y);
  o.z = (unsigned short)f2bf(v.z);
  o.w = (unsigned short)f2bf(v.w);
  *(ushort4*)&outp[(size_t)j * 4] = o;
}

// ========== fused layer v6: exec-masked 2-wide gather, LDS weights, capped occupancy ==========
// One wave per 16-node tile. Lane l: node = r0+(l&15), kg=l>>4 owns cols kg*8+{0..7}, +32.
// grid=512 -> exactly 2 blocks/CU resident (~25% occ): avoids the L2-thrash regime
// measured at 48% occ (FETCH 293 vs 145 MB, WRITE 164 vs 37.5 MB).
__global__ __launch_bounds__(256, 6) void layer_fused_kernel(const int* __restrict__ ofs_i,
                                                             const int* __restrict__ ofs_u,
                                                             const int2* __restrict__ byw_dst,
                                                             const int2* __restrict__ byw_src,
                                                             const float* __restrict__ rs_u,
                                                             const float* __restrict__ rs_i,
                                                             const float* __restrict__ c_i,
                                                             const float* __restrict__ c_u,
                                                             const unsigned short* __restrict__ hu,
                                                             const unsigned short* __restrict__ hi,
                                                             const float* __restrict__ W1,
                                                             const float* __restrict__ b1,
                                                             const float* __restrict__ W2,
                                                             const float* __restrict__ b2,
                                                             unsigned short* __restrict__ hi_new,
                                                             unsigned short* __restrict__ hu_new) {
  __shared__ unsigned short wlds[8192];
  const int tid = threadIdx.x;
  const int lane = tid & 63;
  const int row16 = lane & 15;
  const int kg = lane >> 4;  // 0..3
  for (int ch = tid; ch < 1024; ch += 256) {
    const int w = ch >> 9;
    const int rem = ch & 511;
    const int nb = rem >> 7, kb = (rem >> 6) & 1, l2 = rem & 63;
    const int r16 = l2 & 15, kg2 = l2 >> 4;
    const float* W = w ? W2 : W1;
    unsigned short* dstp = &wlds[ch * 8];
#pragma unroll
    for (int j = 0; j < 8; ++j)
      dstp[j] = (unsigned short)f2bf(W[(kb * 32 + kg2 * 8 + j) * 64 + nb * 16 + r16]);
  }
  __syncthreads();

  float bsum[4];
#pragma unroll
  for (int nb = 0; nb < 4; ++nb) bsum[nb] = b1[nb * 16 + row16] + b2[nb * 16 + row16];

  const int wid = (blockIdx.x * 256 + tid) >> 6;
  const int nwaves = (gridDim.x * 256) >> 6;

  for (int t = wid; t < NTI + NTU; t += nwaves) {
    const bool item = t < NTI;
    const int tt = item ? t : t - NTI;
    const int* ofs = item ? ofs_i : ofs_u;
    const int2* pay = item ? byw_dst : byw_src;
    const float* rsw = item ? rs_i : rs_u;
    const float* cc = item ? c_i : c_u;
    const unsigned short* hs = item ? hu : hi;   // gather source
    const unsigned short* hold = item ? hi : hu;
    unsigned short* hnew = item ? hi_new : hu_new;
    const int r0 = tt * 16;
    const int node = r0 + row16;

    const int lo = ofs[node], hiE = ofs[node + 1];

    float a0[8] = {0.f, 0.f, 0.f, 0.f, 0.f, 0.f, 0.f, 0.f};
    float a1[8] = {0.f, 0.f, 0.f, 0.f, 0.f, 0.f, 0.f, 0.f};
    int i = lo;
    // 2-wide main loop: only real edges, hardware exec-masking for finished lanes
    while (i + 1 < hiE) {
      const int2 p0 = pay[i];
      const int2 p1 = pay[i + 1];
      const float w0 = __builtin_bit_cast(float, p0.y);
      const float w1 = __builtin_bit_cast(float, p1.y);
      const unsigned short* hp0 = hs + (size_t)p0.x * 64 + kg * 8;
      const unsigned short* hp1 = hs + (size_t)p1.x * 64 + kg * 8;
      const u16x8 r0a = *(const u16x8*)hp0;
      const u16x8 r0b = *(const u16x8*)(hp0 + 32);
      const u16x8 r1a = *(const u16x8*)hp1;
      const u16x8 r1b = *(const u16x8*)(hp1 + 32);
#pragma unroll
      for (int j = 0; j < 8; ++j) {
        a0[j] += w0 * bf2f(r0a[j]) + w1 * bf2f(r1a[j]);
        a1[j] += w0 * bf2f(r0b[j]) + w1 * bf2f(r1b[j]);
      }
      i += 2;
    }
    if (i < hiE) {  // odd tail
      const int2 p0 = pay[i];
      const float w0 = __builtin_bit_cast(float, p0.y);
      const unsigned short* hp0 = hs + (size_t)p0.x * 64 + kg * 8;
      const u16x8 r0a = *(const u16x8*)hp0;
      const u16x8 r0b = *(const u16x8*)(hp0 + 32);
#pragma unroll
      for (int j = 0; j < 8; ++j) {
        a0[j] += w0 * bf2f(r0a[j]);
        a1[j] += w0 * bf2f(r0b[j]);
      }
    }

    const float rsn = rsw[node];
    const float cnode = cc[node];
    const unsigned short* hp = hold + (size_t)node * 64 + kg * 8;
    const u16x8 hv0 = *(const u16x8*)hp;
    const u16x8 hv1 = *(const u16x8*)(hp + 32);
    bf16x8 ag[2], ap[2];
#pragma unroll
    for (int j = 0; j < 8; ++j) {
      const float g0 = a0[j] * rsn;
      const float g1 = a1[j] * rsn;
      ag[0][j] = f2bf(g0);
      ag[1][j] = f2bf(g1);
      ap[0][j] = f2bf(g0 * bf2f(hv0[j]));
      ap[1][j] = f2bf(g1 * bf2f(hv1[j]));
    }

    f32x4 acc[4];
#pragma unroll
    for (int nb = 0; nb < 4; ++nb) acc[nb] = (f32x4){0.f, 0.f, 0.f, 0.f};
    const unsigned short* wl = wlds + lane * 8;
#pragma unroll
    for (int nb = 0; nb < 4; ++nb)
#pragma unroll
      for (int kb = 0; kb < 2; ++kb) {
        const bf16x8 w1f = *(const bf16x8*)(wl + ((0 * 4 + nb) * 2 + kb) * 512);
        const bf16x8 w2f = *(const bf16x8*)(wl + ((1 * 4 + nb) * 2 + kb) * 512);
        acc[nb] = __builtin_amdgcn_mfma_f32_16x16x32_bf16(ag[kb], w1f, acc[nb], 0, 0, 0);
        acc[nb] = __builtin_amdgcn_mfma_f32_16x16x32_bf16(ap[kb], w2f, acc[nb], 0, 0, 0);
      }

    float cv[4];
#pragma unroll
    for (int reg = 0; reg < 4; ++reg) cv[reg] = __shfl(cnode, kg * 4 + reg);
    float v[4][4];
    float ss[4] = {0.f, 0.f, 0.f, 0.f};
#pragma unroll
    for (int nb = 0; nb < 4; ++nb)
#pragma unroll
      for (int reg = 0; reg < 4; ++reg) {
        float x = acc[nb][reg] + cv[reg] * bsum[nb];
        x = (x > 0.f) ? x : 0.2f * x;
        v[nb][reg] = x;
        ss[reg] += x * x;
      }
#pragma unroll
    for (int m = 1; m < 16; m <<= 1)
#pragma unroll
      for (int reg = 0; reg < 4; ++reg) ss[reg] += __shfl_xor(ss[reg], m);
#pragma unroll
    for (int reg = 0; reg < 4; ++reg) {
      const float inv = 1.0f / fmaxf(sqrtf(ss[reg]), 1e-12f);
      const size_t rowbase = (size_t)(r0 + kg * 4 + reg) * 64;
#pragma unroll
      for (int nb = 0; nb < 4; ++nb)
        hnew[rowbase + nb * 16 + row16] = (unsigned short)f2bf(v[nb][reg] * inv);
    }
  }
}

// ================= output gathers =================
__global__ __launch_bounds__(256) void gather_f32_kernel(const float* __restrict__ hu,
                                                         const float* __restrict__ hi,
                                                         const int* __restrict__ users,
                                                         const int* __restrict__ pos,
                                                         const int* __restrict__ neg,
                                                         float* __restrict__ out) {
  int t = blockIdx.x * 256 + threadIdx.x;
  if (t >= 3 * NB * 64) return;
  int j = t & 63;
  int b = (t >> 6) & (NB - 1);
  int which = t / (NB * 64);
  int row = (which == 0) ? users[b] : ((which == 1) ? pos[b] : neg[b]);
  const float* h = (which == 0) ? hu : hi;
  out[(size_t)which * NB * 256 + (size_t)b * 256 + j] = h[(size_t)row * 64 + j];
}

__global__ __launch_bounds__(256) void gather_bf_kernel(const unsigned short* __restrict__ hu,
                                                        const unsigned short* __restrict__ hi,
                                                        const int* __restrict__ users,
                                                        const int* __restrict__ pos,
                                                        const int* __restrict__ neg,
                                                        float* __restrict__ out, int stage) {
  int t = blockIdx.x * 256 + threadIdx.x;
  if (t >= 3 * NB * 64) return;
  int j = t & 63;
  int b = (t >> 6) & (NB - 1);
  int which = t / (NB * 64);
  int row = (which == 0) ? users[b] : ((which == 1) ? pos[b] : neg[b]);
  const unsigned short* h = (which == 0) ? hu : hi;
  out[(size_t)which * NB * 256 + (size_t)b * 256 + (size_t)stage * 64 + j] =
      bf2f(h[(size_t)row * 64 + j]);
}

extern "C" void kernel_launch(void* const* d_in, const int* in_sizes, int n_in,
                              void* d_out, int out_size, void* d_ws, size_t ws_size,
                              hipStream_t stream) {
  (void)in_sizes; (void)n_in; (void)out_size; (void)ws_size;
  const float* user_feat = (const float*)d_in[0];
  const float* item_feat = (const float*)d_in[1];
  const float* W1 = (const float*)d_in[2];
  const float* b1 = (const float*)d_in[3];
  const float* W2 = (const float*)d_in[4];
  const float* b2 = (const float*)d_in[5];
  const int* edge_src = (const int*)d_in[6];
  const int* edge_dst = (const int*)d_in[7];
  const int* users = (const int*)d_in[8];
  const int* pos_items = (const int*)d_in[9];
  const int* neg_items = (const int*)d_in[10];
  float* out = (float*)d_out;

  char* base = (char*)d_ws;
  size_t ofsz = 0;
  auto alloc = [&](size_t bytes) -> char* {
    char* r = base + ofsz;
    ofsz += (bytes + 1023) & ~(size_t)1023;
    return r;
  };
  int* ofs_u = (int*)alloc((NU + 1) * 4);
  int* ofs_i = (int*)alloc((NI + 1) * 4);
  int* gcur_s = (int*)alloc(128 * 4);
  int* gcur_d = (int*)alloc(128 * 4);
  int* bktofs_s = (int*)alloc(128 * 4);
  int* bktofs_d = (int*)alloc(128 * 4);
  int2* temp_s = (int2*)alloc((size_t)NBS * CAP * 8);
  int2* temp_d = (int2*)alloc((size_t)NBD * CAP * 8);
  int* by_src = (int*)alloc((size_t)NE * 4);
  int* by_dst = (int*)alloc((size_t)NE * 4);
  int2* byw_src = (int2*)alloc((size_t)NE * 8);
  int2* byw_dst = (int2*)alloc((size_t)NE * 8);
  float* rs_u = (float*)alloc((size_t)NU * 4);
  float* rs_i = (float*)alloc((size_t)NI * 4);
  float* c_u = (float*)alloc((size_t)NU * 4);
  float* c_i = (float*)alloc((size_t)NI * 4);
  unsigned short* hbU0 = (unsigned short*)alloc((size_t)NU * 64 * 2);
  unsigned short* hbU1 = (unsigned short*)alloc((size_t)NU * 64 * 2);
  unsigned short* hbI0 = (unsigned short*)alloc((size_t)NI * 64 * 2);
  unsigned short* hbI1 = (unsigned short*)alloc((size_t)NI * 64 * 2);

  unsigned short* bufU[2] = {hbU1, hbU0};
  unsigned short* bufI[2] = {hbI1, hbI0};

  hipMemsetAsync(gcur_s, 0, 128 * 4, stream);
  hipMemsetAsync(gcur_d, 0, 128 * 4, stream);
  binA_kernel<<<1024, 256, 0, stream>>>(edge_src, edge_dst, gcur_s, gcur_d, temp_s, temp_d);
  bktscan_kernel<<<1, 64, 0, stream>>>(gcur_s, gcur_d, bktofs_s, bktofs_d, ofs_u, ofs_i);
  placeB_kernel<<<NBS + NBD, 256, 0, stream>>>(temp_s, temp_d, gcur_s, gcur_d,
                                               bktofs_s, bktofs_d, ofs_u, ofs_i,
                                               rs_u, rs_i, by_src, by_dst);
  cw_kernel<<<(NI + NU + 255) / 256, 256, 0, stream>>>(ofs_i, ofs_u, by_dst, by_src,
                                                       rs_u, rs_i, byw_dst, byw_src, c_i, c_u);

  conv_kernel<<<((NU + NI) * 16 + 255) / 256, 256, 0, stream>>>(user_feat, item_feat, hbU0, hbI0);

  gather_f32_kernel<<<(3 * NB * 64 + 255) / 256, 256, 0, stream>>>(
      user_feat, item_feat, users, pos_items, neg_items, out);

  const unsigned short* hu = hbU0;
  const unsigned short* hi = hbI0;
  for (int l = 0; l < 3; ++l) {
    unsigned short* hu_new = bufU[l & 1];
    unsigned short* hi_new = bufI[l & 1];
    layer_fused_kernel<<<512, 256, 0, stream>>>(ofs_i, ofs_u, byw_dst, byw_src,
                                                rs_u, rs_i, c_i, c_u,
                                                hu, hi,
                                                W1 + l * 4096, b1 + l * 64,
                                                W2 + l * 4096, b2 + l * 64,
                                                hi_new, hu_new);
    gather_bf_kernel<<<(3 * NB * 64 + 255) / 256, 256, 0, stream>>>(
        hu_new, hi_new, users, pos_items, neg_items, out, l + 1);
    hu = hu_new;
    hi = hi_new;
  }
}

// Round 14
// 415.065 us; speedup vs baseline: 1.2880x; 1.2880x over previous
//
#include <hip/hip_runtime.h>

#define NU 100000
#define NI 200000
#define NE 1000000
#define NB 4096
#define CAP 16384
#define NBS 98   // src buckets: ceil(100000/1024), shift 10
#define NBD 98   // dst buckets: ceil(200000/2048), shift 11
#define NTI (NI / 16)
#define NTU (NU / 16)

typedef __attribute__((ext_vector_type(8))) short bf16x8;
typedef __attribute__((ext_vector_type(4))) float f32x4;
typedef __attribute__((ext_vector_type(8))) unsigned short u16x8;

static __device__ __forceinline__ short f2bf(float f) {
  unsigned u = __builtin_bit_cast(unsigned, f);
  unsigned r = (u + 0x7fffu + ((u >> 16) & 1u)) >> 16;
  return (short)r;
}
static __device__ __forceinline__ float bf2f(unsigned short u) {
  return __builtin_bit_cast(float, ((unsigned)u) << 16);
}

// ====== binA: per-block LDS histogram + run reservation + direct scatter to bucket arena ======
__global__ __launch_bounds__(256) void binA_kernel(const int* __restrict__ src,
                                                   const int* __restrict__ dst,
                                                   int* __restrict__ gcur_s,
                                                   int* __restrict__ gcur_d,
                                                   int2* __restrict__ temp_s,
                                                   int2* __restrict__ temp_d) {
  __shared__ int lh[128], lbase[128], lpos[128];
  const int dir = blockIdx.x >> 9;          // 0 = src, 1 = dst
  const int cb = blockIdx.x & 511;
  const int lo = (int)(((long long)NE * cb) >> 9);
  const int hi = (int)(((long long)NE * (cb + 1)) >> 9);
  const int* key = dir ? dst : src;
  const int* oth = dir ? src : dst;
  int* gcur = dir ? gcur_d : gcur_s;
  int2* temp = dir ? temp_d : temp_s;
  const int shift = dir ? 11 : 10;
  const int tid = threadIdx.x;
  if (tid < 128) lh[tid] = 0;
  __syncthreads();
  for (int e = lo + tid; e < hi; e += 256) atomicAdd(&lh[key[e] >> shift], 1);
  __syncthreads();
  if (tid < 128) {
    const int c = lh[tid];
    lbase[tid] = c ? atomicAdd(&gcur[tid], c) : 0;
    lpos[tid] = 0;
  }
  __syncthreads();
  for (int e = lo + tid; e < hi; e += 256) {
    const int k = key[e];
    const int b = k >> shift;
    const int p = lbase[b] + atomicAdd(&lpos[b], 1);
    temp[(size_t)b * CAP + p] = make_int2(k, oth[e]);
  }
}

// ====== tiny serial scan of bucket totals ======
__global__ void bktscan_kernel(const int* __restrict__ gcur_s, const int* __restrict__ gcur_d,
                               int* __restrict__ bktofs_s, int* __restrict__ bktofs_d,
                               int* __restrict__ ofs_u, int* __restrict__ ofs_i) {
  const int t = threadIdx.x;
  if (t == 0) {
    int a = 0;
    for (int i = 0; i < NBS; ++i) { bktofs_s[i] = a; a += gcur_s[i]; }
    bktofs_s[NBS] = a;
    ofs_u[NU] = NE;
  }
  if (t == 1) {
    int a = 0;
    for (int i = 0; i < NBD; ++i) { bktofs_d[i] = a; a += gcur_d[i]; }
    bktofs_d[NBD] = a;
    ofs_i[NI] = NE;
  }
}

// ====== placeB: per-bucket LDS counting sort -> ofs, rs, srs, CSR payload (nbr only, 4B) ======
__global__ __launch_bounds__(256) void placeB_kernel(const int2* __restrict__ temp_s,
                                                     const int2* __restrict__ temp_d,
                                                     const int* __restrict__ gcur_s,
                                                     const int* __restrict__ gcur_d,
                                                     const int* __restrict__ bktofs_s,
                                                     const int* __restrict__ bktofs_d,
                                                     int* __restrict__ ofs_u, int* __restrict__ ofs_i,
                                                     float* __restrict__ rs_u, float* __restrict__ rs_i,
                                                     float* __restrict__ srs_u, float* __restrict__ srs_i,
                                                     int* __restrict__ by_src, int* __restrict__ by_dst) {
  __shared__ int cnt[2048];
  __shared__ int exc[2048];
  __shared__ int wsum[256];
  const bool isdst = blockIdx.x >= NBS;
  const int b = isdst ? (int)blockIdx.x - NBS : (int)blockIdx.x;
  const int shift = isdst ? 11 : 10;
  const int nodelo = b << shift;
  const int n = isdst ? NI : NU;
  const int2* temp = (isdst ? temp_d : temp_s) + (size_t)b * CAP;
  const int ecnt = (isdst ? gcur_d : gcur_s)[b];
  const int bbase = (isdst ? bktofs_d : bktofs_s)[b];
  int* ofs = isdst ? ofs_i : ofs_u;
  float* rs = isdst ? rs_i : rs_u;
  float* srs = isdst ? srs_i : srs_u;
  int* by = isdst ? by_dst : by_src;
  const int tid = threadIdx.x;
  const int NN = 1 << shift;  // 1024 or 2048

  for (int j = tid; j < NN; j += 256) cnt[j] = 0;
  __syncthreads();
  for (int k = tid; k < ecnt; k += 256) atomicAdd(&cnt[temp[k].x - nodelo], 1);
  __syncthreads();
  const int per = NN >> 8;  // 4 or 8
  int s = 0;
  for (int j = 0; j < per; ++j) s += cnt[tid * per + j];
  wsum[tid] = s;
  __syncthreads();
  for (int off = 1; off < 256; off <<= 1) {
    int t2 = (tid >= off) ? wsum[tid - off] : 0;
    __syncthreads();
    wsum[tid] += t2;
    __syncthreads();
  }
  int run = wsum[tid] - s;
  for (int j = 0; j < per; ++j) {
    const int idx = tid * per + j;
    exc[idx] = run;
    run += cnt[idx];
  }
  __syncthreads();
  for (int j = tid; j < NN; j += 256) {
    const int node = nodelo + j;
    if (node < n) {
      ofs[node] = bbase + exc[j];
      const int d = cnt[j];
      rs[node] = d > 0 ? rsqrtf((float)d) : 0.f;
      srs[node] = d > 0 ? sqrtf((float)d) : 0.f;
    }
  }
  __syncthreads();
  for (int j = tid; j < NN; j += 256) cnt[j] = exc[j];  // cnt becomes cursor
  __syncthreads();
  for (int k = tid; k < ecnt; k += 256) {
    const int2 t2 = temp[k];
    const int p = bbase + atomicAdd(&cnt[t2.x - nodelo], 1);
    by[p] = t2.y;
  }
}

// ====== c: layer-invariant c = rs_r * sum rs_nb ======
__global__ __launch_bounds__(256) void c_kernel(const int* __restrict__ ofs_i,
                                                const int* __restrict__ ofs_u,
                                                const int* __restrict__ by_dst,
                                                const int* __restrict__ by_src,
                                                const float* __restrict__ rs_u,
                                                const float* __restrict__ rs_i,
                                                float* __restrict__ c_i,
                                                float* __restrict__ c_u) {
  int r = blockIdx.x * 256 + threadIdx.x;
  if (r < NI) {
    const int lo = ofs_i[r], hi = ofs_i[r + 1];
    float s = 0.f;
    for (int k = lo; k < hi; ++k) s += rs_u[by_dst[k]];
    c_i[r] = rs_i[r] * s;
  } else if (r < NI + NU) {
    r -= NI;
    const int lo = ofs_u[r], hi = ofs_u[r + 1];
    float s = 0.f;
    for (int k = lo; k < hi; ++k) s += rs_i[by_src[k]];
    c_u[r] = rs_u[r] * s;
  }
}

// ====== conv: hs = bf16( f32_h * rs )  (pre-scaled state; the ONLY per-layer array) ======
__global__ __launch_bounds__(256) void conv_kernel(const float* __restrict__ uf,
                                                   const float* __restrict__ itf,
                                                   const float* __restrict__ rs_u,
                                                   const float* __restrict__ rs_i,
                                                   unsigned short* __restrict__ hsu,
                                                   unsigned short* __restrict__ hsi) {
  int i = blockIdx.x * 256 + threadIdx.x;
  const int n4u = NU * 16;
  const float* in;
  const float* rs;
  unsigned short* outp;
  int j;
  if (i < n4u) {
    in = uf; rs = rs_u; outp = hsu; j = i;
  } else if (i < n4u + NI * 16) {
    in = itf; rs = rs_i; outp = hsi; j = i - n4u;
  } else return;
  const float rsn = rs[j >> 4];
  float4 v = *(const float4*)&in[(size_t)j * 4];
  ushort4 o;
  o.x = (unsigned short)f2bf(v.x * rsn);
  o.y = (unsigned short)f2bf(v.y * rsn);
  o.z = (unsigned short)f2bf(v.z * rsn);
  o.w = (unsigned short)f2bf(v.w * rsn);
  *(ushort4*)&outp[(size_t)j * 4] = o;
}

// ========== fused layer v7 (r8 structure, hs-only state): ==========
// a = sum_nb hs_nb ; ag = a*rs_node ; ap = a (.) hs_own  [scaling cancels] ;
// y = leaky(ag@W1 + ap@W2 + c*b) ; hs_new = y * inv_norm * rs_node.
// One wave per 16-node tile; 4x chunked gather with wt-masked dummy loads (r8's 111us loop).
__global__ __launch_bounds__(256) void layer_fused_kernel(const int* __restrict__ ofs_i,
                                                          const int* __restrict__ ofs_u,
                                                          const int* __restrict__ by_dst,
                                                          const int* __restrict__ by_src,
                                                          const float* __restrict__ rs_u,
                                                          const float* __restrict__ rs_i,
                                                          const float* __restrict__ c_i,
                                                          const float* __restrict__ c_u,
                                                          const unsigned short* __restrict__ hsu,
                                                          const unsigned short* __restrict__ hsi,
                                                          const float* __restrict__ W1,
                                                          const float* __restrict__ b1,
                                                          const float* __restrict__ W2,
                                                          const float* __restrict__ b2,
                                                          unsigned short* __restrict__ hsi_new,
                                                          unsigned short* __restrict__ hsu_new) {
  __shared__ unsigned short wlds[8192];
  const int tid = threadIdx.x;
  const int lane = tid & 63;
  const int row16 = lane & 15;
  const int kg = lane >> 4;  // 0..3
  for (int ch = tid; ch < 1024; ch += 256) {
    const int w = ch >> 9;
    const int rem = ch & 511;
    const int nb = rem >> 7, kb = (rem >> 6) & 1, l2 = rem & 63;
    const int r16 = l2 & 15, kg2 = l2 >> 4;
    const float* W = w ? W2 : W1;
    unsigned short* dstp = &wlds[ch * 8];
#pragma unroll
    for (int j = 0; j < 8; ++j)
      dstp[j] = (unsigned short)f2bf(W[(kb * 32 + kg2 * 8 + j) * 64 + nb * 16 + r16]);
  }
  __syncthreads();

  float bsum[4];
#pragma unroll
  for (int nb = 0; nb < 4; ++nb) bsum[nb] = b1[nb * 16 + row16] + b2[nb * 16 + row16];

  const int wid = (blockIdx.x * 256 + tid) >> 6;
  const int nwaves = (gridDim.x * 256) >> 6;

  for (int t = wid; t < NTI + NTU; t += nwaves) {
    const bool item = t < NTI;
    const int tt = item ? t : t - NTI;
    const int* ofs = item ? ofs_i : ofs_u;
    const int* pay = item ? by_dst : by_src;
    const float* rsw = item ? rs_i : rs_u;
    const float* cc = item ? c_i : c_u;
    const unsigned short* hs = item ? hsu : hsi;     // gather source (other side)
    const unsigned short* hsown = item ? hsi : hsu;  // own row
    unsigned short* hsnew = item ? hsi_new : hsu_new;
    const int r0 = tt * 16;
    const int node = r0 + row16;

    const int lo = ofs[node], hiE = ofs[node + 1];
    int rounds = (hiE - lo + 3) >> 2;
#pragma unroll
    for (int m = 1; m < 16; m <<= 1) rounds = max(rounds, __shfl_xor(rounds, m));

    float a0[8] = {0.f, 0.f, 0.f, 0.f, 0.f, 0.f, 0.f, 0.f};
    float a1[8] = {0.f, 0.f, 0.f, 0.f, 0.f, 0.f, 0.f, 0.f};
    for (int rd = 0; rd < rounds; ++rd) {
      const int i0 = lo + rd * 4;
      int nb4[4];
      float wt[4];
#pragma unroll
      for (int s = 0; s < 4; ++s) {
        const int idx = i0 + s;
        nb4[s] = pay[min(idx, NE - 1)];
        wt[s] = (idx < hiE) ? 1.f : 0.f;
      }
      u16x8 h0[4], h1[4];
#pragma unroll
      for (int s = 0; s < 4; ++s) {
        const unsigned short* hp = hs + (size_t)nb4[s] * 64 + kg * 8;
        h0[s] = *(const u16x8*)hp;
        h1[s] = *(const u16x8*)(hp + 32);
      }
#pragma unroll
      for (int s = 0; s < 4; ++s)
#pragma unroll
        for (int j = 0; j < 8; ++j) {
          a0[j] += wt[s] * bf2f(h0[s][j]);
          a1[j] += wt[s] * bf2f(h1[s][j]);
        }
    }

    const float rsn = rsw[node];
    const float cnode = cc[node];
    const unsigned short* hp = hsown + (size_t)node * 64 + kg * 8;
    const u16x8 hv0 = *(const u16x8*)hp;
    const u16x8 hv1 = *(const u16x8*)(hp + 32);
    bf16x8 ag[2], ap[2];
#pragma unroll
    for (int j = 0; j < 8; ++j) {
      ag[0][j] = f2bf(a0[j] * rsn);
      ag[1][j] = f2bf(a1[j] * rsn);
      ap[0][j] = f2bf(a0[j] * bf2f(hv0[j]));   // p = a (.) hs_own (scaling cancels)
      ap[1][j] = f2bf(a1[j] * bf2f(hv1[j]));
    }

    f32x4 acc[4];
#pragma unroll
    for (int nb = 0; nb < 4; ++nb) acc[nb] = (f32x4){0.f, 0.f, 0.f, 0.f};
    const unsigned short* wl = wlds + lane * 8;
#pragma unroll
    for (int nb = 0; nb < 4; ++nb)
#pragma unroll
      for (int kb = 0; kb < 2; ++kb) {
        const bf16x8 w1f = *(const bf16x8*)(wl + ((0 * 4 + nb) * 2 + kb) * 512);
        const bf16x8 w2f = *(const bf16x8*)(wl + ((1 * 4 + nb) * 2 + kb) * 512);
        acc[nb] = __builtin_amdgcn_mfma_f32_16x16x32_bf16(ag[kb], w1f, acc[nb], 0, 0, 0);
        acc[nb] = __builtin_amdgcn_mfma_f32_16x16x32_bf16(ap[kb], w2f, acc[nb], 0, 0, 0);
      }

    float cv[4], rsrow[4];
#pragma unroll
    for (int reg = 0; reg < 4; ++reg) {
      cv[reg] = __shfl(cnode, kg * 4 + reg);
      rsrow[reg] = __shfl(rsn, kg * 4 + reg);
    }
    float v[4][4];
    float ss[4] = {0.f, 0.f, 0.f, 0.f};
#pragma unroll
    for (int nb = 0; nb < 4; ++nb)
#pragma unroll
      for (int reg = 0; reg < 4; ++reg) {
        float x = acc[nb][reg] + cv[reg] * bsum[nb];
        x = (x > 0.f) ? x : 0.2f * x;
        v[nb][reg] = x;
        ss[reg] += x * x;
      }
#pragma unroll
    for (int m = 1; m < 16; m <<= 1)
#pragma unroll
      for (int reg = 0; reg < 4; ++reg) ss[reg] += __shfl_xor(ss[reg], m);
#pragma unroll
    for (int reg = 0; reg < 4; ++reg) {
      const float invs = rsrow[reg] / fmaxf(sqrtf(ss[reg]), 1e-12f);
      const size_t rowbase = (size_t)(r0 + kg * 4 + reg) * 64;
#pragma unroll
      for (int nb = 0; nb < 4; ++nb)
        hsnew[rowbase + nb * 16 + row16] = (unsigned short)f2bf(v[nb][reg] * invs);
    }
  }
}

// ================= output gathers =================
__global__ __launch_bounds__(256) void gather_f32_kernel(const float* __restrict__ hu,
                                                         const float* __restrict__ hi,
                                                         const int* __restrict__ users,
                                                         const int* __restrict__ pos,
                                                         const int* __restrict__ neg,
                                                         float* __restrict__ out) {
  int t = blockIdx.x * 256 + threadIdx.x;
  if (t >= 3 * NB * 64) return;
  int j = t & 63;
  int b = (t >> 6) & (NB - 1);
  int which = t / (NB * 64);
  int row = (which == 0) ? users[b] : ((which == 1) ? pos[b] : neg[b]);
  const float* h = (which == 0) ? hu : hi;
  out[(size_t)which * NB * 256 + (size_t)b * 256 + j] = h[(size_t)row * 64 + j];
}

// out = hs[row] * sqrt(deg)  (reconstruct normalized h from pre-scaled state)
__global__ __launch_bounds__(256) void gather_bf_kernel(const unsigned short* __restrict__ hsu,
                                                        const unsigned short* __restrict__ hsi,
                                                        const float* __restrict__ srs_u,
                                                        const float* __restrict__ srs_i,
                                                        const int* __restrict__ users,
                                                        const int* __restrict__ pos,
                                                        const int* __restrict__ neg,
                                                        float* __restrict__ out, int stage) {
  int t = blockIdx.x * 256 + threadIdx.x;
  if (t >= 3 * NB * 64) return;
  int j = t & 63;
  int b = (t >> 6) & (NB - 1);
  int which = t / (NB * 64);
  int row = (which == 0) ? users[b] : ((which == 1) ? pos[b] : neg[b]);
  const unsigned short* h = (which == 0) ? hsu : hsi;
  const float s = (which == 0) ? srs_u[row] : srs_i[row];
  out[(size_t)which * NB * 256 + (size_t)b * 256 + (size_t)stage * 64 + j] =
      bf2f(h[(size_t)row * 64 + j]) * s;
}

extern "C" void kernel_launch(void* const* d_in, const int* in_sizes, int n_in,
                              void* d_out, int out_size, void* d_ws, size_t ws_size,
                              hipStream_t stream) {
  (void)in_sizes; (void)n_in; (void)out_size; (void)ws_size;
  const float* user_feat = (const float*)d_in[0];
  const float* item_feat = (const float*)d_in[1];
  const float* W1 = (const float*)d_in[2];
  const float* b1 = (const float*)d_in[3];
  const float* W2 = (const float*)d_in[4];
  const float* b2 = (const float*)d_in[5];
  const int* edge_src = (const int*)d_in[6];
  const int* edge_dst = (const int*)d_in[7];
  const int* users = (const int*)d_in[8];
  const int* pos_items = (const int*)d_in[9];
  const int* neg_items = (const int*)d_in[10];
  float* out = (float*)d_out;

  char* base = (char*)d_ws;
  size_t ofsz = 0;
  auto alloc = [&](size_t bytes) -> char* {
    char* r = base + ofsz;
    ofsz += (bytes + 1023) & ~(size_t)1023;
    return r;
  };
  int* ofs_u = (int*)alloc((NU + 1) * 4);
  int* ofs_i = (int*)alloc((NI + 1) * 4);
  int* gcur_s = (int*)alloc(128 * 4);
  int* gcur_d = (int*)alloc(128 * 4);
  int* bktofs_s = (int*)alloc(128 * 4);
  int* bktofs_d = (int*)alloc(128 * 4);
  int2* temp_s = (int2*)alloc((size_t)NBS * CAP * 8);
  int2* temp_d = (int2*)alloc((size_t)NBD * CAP * 8);
  int* by_src = (int*)alloc((size_t)NE * 4);
  int* by_dst = (int*)alloc((size_t)NE * 4);
  float* rs_u = (float*)alloc((size_t)NU * 4);
  float* rs_i = (float*)alloc((size_t)NI * 4);
  float* srs_u = (float*)alloc((size_t)NU * 4);
  float* srs_i = (float*)alloc((size_t)NI * 4);
  float* c_u = (float*)alloc((size_t)NU * 4);
  float* c_i = (float*)alloc((size_t)NI * 4);
  unsigned short* hsU0 = (unsigned short*)alloc((size_t)NU * 64 * 2);
  unsigned short* hsU1 = (unsigned short*)alloc((size_t)NU * 64 * 2);
  unsigned short* hsI0 = (unsigned short*)alloc((size_t)NI * 64 * 2);
  unsigned short* hsI1 = (unsigned short*)alloc((size_t)NI * 64 * 2);

  unsigned short* bufU[2] = {hsU1, hsU0};
  unsigned short* bufI[2] = {hsI1, hsI0};

  hipMemsetAsync(gcur_s, 0, 128 * 4, stream);
  hipMemsetAsync(gcur_d, 0, 128 * 4, stream);
  binA_kernel<<<1024, 256, 0, stream>>>(edge_src, edge_dst, gcur_s, gcur_d, temp_s, temp_d);
  bktscan_kernel<<<1, 64, 0, stream>>>(gcur_s, gcur_d, bktofs_s, bktofs_d, ofs_u, ofs_i);
  placeB_kernel<<<NBS + NBD, 256, 0, stream>>>(temp_s, temp_d, gcur_s, gcur_d,
                                               bktofs_s, bktofs_d, ofs_u, ofs_i,
                                               rs_u, rs_i, srs_u, srs_i, by_src, by_dst);
  c_kernel<<<(NI + NU + 255) / 256, 256, 0, stream>>>(ofs_i, ofs_u, by_dst, by_src,
                                                      rs_u, rs_i, c_i, c_u);

  conv_kernel<<<((NU + NI) * 16 + 255) / 256, 256, 0, stream>>>(
      user_feat, item_feat, rs_u, rs_i, hsU0, hsI0);

  gather_f32_kernel<<<(3 * NB * 64 + 255) / 256, 256, 0, stream>>>(
      user_feat, item_feat, users, pos_items, neg_items, out);

  const unsigned short* hsu = hsU0;
  const unsigned short* hsi = hsI0;
  for (int l = 0; l < 3; ++l) {
    unsigned short* hsu_new = bufU[l & 1];
    unsigned short* hsi_new = bufI[l & 1];
    layer_fused_kernel<<<2048, 256, 0, stream>>>(ofs_i, ofs_u, by_dst, by_src,
                                                 rs_u, rs_i, c_i, c_u,
                                                 hsu, hsi,
                                                 W1 + l * 4096, b1 + l * 64,
                                                 W2 + l * 4096, b2 + l * 64,
                                                 hsi_new, hsu_new);
    gather_bf_kernel<<<(3 * NB * 64 + 255) / 256, 256, 0, stream>>>(
        hsu_new, hsi_new, srs_u, srs_i, users, pos_items, neg_items, out, l + 1);
    hsu = hsu_new;
    hsi = hsi_new;
  }
}